// Round 1
// 774.815 us; speedup vs baseline: 1.5299x; 1.5299x over previous
//
#include <hip/hip_runtime.h>
#include <hip/hip_cooperative_groups.h>
#include <cmath>

// ---------------- problem constants ----------------
#define FEAT  192
#define CINCH 384          // CIN
#define CGATE 768
#define BATCH 16
#define HH    64
#define WW    64
#define NP    (BATCH*HH*WW)   // 65536 flattened (b,y,w)
#define KI2S  768             // 384 ic * 2 live taps
#define KS2S  576             // 192 feat * 3 taps
#define NBLK  192             // scan blocks: 16 batches x 12 f-chunks

using bf16   = __bf16;
using bf16x8 = __attribute__((ext_vector_type(8))) __bf16;
using bf16x4 = __attribute__((ext_vector_type(4))) __bf16;
using f32x4  = __attribute__((ext_vector_type(4))) float;
typedef unsigned long long u64;

// ---------------------------------------------------------------
// IC-coherent accessors: relaxed agent-scope atomics compile to plain
// global_load/store with sc0/sc1 flags (bypass L1+L2, hit Infinity
// Cache = the cross-XCD coherence point). NO buffer_wbl2 / buffer_inv
// cache-wide maintenance ops are emitted (those come from acq/rel
// fences only). Visibility rule used below: sc1 store completion
// (vmcnt==0) => visible at IC => visible to any sc1 load.
// ---------------------------------------------------------------
__device__ __forceinline__ void ic_store64(u64* p, u64 v) {
    __hip_atomic_store(p, v, __ATOMIC_RELAXED, __HIP_MEMORY_SCOPE_AGENT);
}
__device__ __forceinline__ u64 ic_load64(const u64* p) {
    return __hip_atomic_load(p, __ATOMIC_RELAXED, __HIP_MEMORY_SCOPE_AGENT);
}

__device__ __forceinline__ float sigm_fast(float v) {
    return __builtin_amdgcn_rcpf(1.f + __expf(-v));
}
__device__ __forceinline__ float tanh_fast(float v) {
    // 1 - 2/(1+e^{2v}); saturates correctly for |v| large (exp->inf/0)
    return 1.f - 2.f * __builtin_amdgcn_rcpf(1.f + __expf(2.f * v));
}

// ============================================================
// Pack weights into bf16 GEMM operand layouts (A row-major, k contiguous).
// ============================================================
__global__ void pack_weights(const float* __restrict__ wi, const float* __restrict__ ws,
                             const float* __restrict__ wk,
                             bf16* __restrict__ WpA, bf16* __restrict__ WpS,
                             bf16* __restrict__ WpK) {
    int tid = blockIdx.x * 256 + threadIdx.x;
    int stride = gridDim.x * 256;
    for (int idx = tid; idx < CGATE * KI2S; idx += stride) {
        int cp = idx / KI2S, k = idx % KI2S;
        int q = cp / 192, r = cp % 192, g = r / 64, f = r % 64;
        int c = g * 256 + q * 64 + f;             // original (pre-shuffle) out channel
        float v;
        if (k < CINCH) {
            v = wi[(c * CINCH + k) * 3 + 0];      // tap0: full
        } else {
            int ic = k - CINCH;                   // tap1: causal group mask
            v = (g >= ic / 128) ? wi[(c * CINCH + ic) * 3 + 1] : 0.f;
        }
        WpA[idx] = (bf16)v;
    }
    for (int idx = tid; idx < CGATE * KS2S; idx += stride) {
        int oc = idx / KS2S, k = idx % KS2S;
        int t = k / FEAT, f = k % FEAT;
        WpS[idx] = (bf16)ws[(oc * FEAT + f) * 3 + t];
    }
    for (int idx = tid; idx < CINCH * FEAT; idx += stride) {
        int co = idx / FEAT, f = idx % FEAT;
        WpK[idx] = (co / 128 >= f / 64) ? (bf16)wk[idx] : (bf16)0.f;
    }
}

// ============================================================
// Pack x (fp32 NCHW) -> Xp bf16 [p=(b,y,w)][k=768]
// ============================================================
__global__ void pack_x(const float* __restrict__ x, bf16* __restrict__ Xp) {
    __shared__ float tile[64][65];
    int b = blockIdx.x >> 6, y = blockIdx.x & 63;
    const float* xb = x + ((size_t)b * CINCH * HH + y) * WW;
    bf16* Xrow = Xp + ((size_t)b * HH * WW + (size_t)y * WW) * KI2S;
    for (int ic0 = 0; ic0 < CINCH; ic0 += 64) {
        for (int rep = 0; rep < 16; ++rep) {
            int idx = rep * 256 + threadIdx.x;
            int i = idx >> 6, w = idx & 63;
            tile[i][w] = xb[(size_t)(ic0 + i) * (HH * WW) + w];
        }
        __syncthreads();
        for (int rep = 0; rep < 16; ++rep) {
            int idx = rep * 256 + threadIdx.x;
            int w = idx >> 6, i = idx & 63;
            Xrow[(size_t)w * KI2S + CINCH + ic0 + i] = (bf16)tile[i][w];
            Xrow[(size_t)w * KI2S + ic0 + i] = (w == 0) ? (bf16)0.f : (bf16)tile[i][w - 1];
        }
        __syncthreads();
    }
}

// ============================================================
// i2s GEMM: Hbuf[c'][p] = sum_k WpA[c'][k] * Xp[p][k]  (unchanged, verified)
// ============================================================
__global__ __launch_bounds__(256) void gemm_i2s(const bf16* __restrict__ A,
                                                const bf16* __restrict__ B,
                                                bf16* __restrict__ Hout) {
    __shared__ __align__(16) bf16 As[128 * 64];
    __shared__ __align__(16) bf16 Bs[128 * 64];
    const int m0 = blockIdx.y * 128;
    const int p0 = blockIdx.x * 128;
    const int tid = threadIdx.x;
    const int lane = tid & 63, wid = tid >> 6;
    const int quad = lane >> 4, col = lane & 15;
    const int mhalf = (wid & 1) * 64, nhalf = (wid >> 1) * 64;
    f32x4 acc[4][4] = {};
    for (int k0 = 0; k0 < KI2S; k0 += 64) {
        for (int r = 0; r < 4; ++r) {
            int L = r * 256 + tid;
            int row = L >> 3, slot = L & 7;
            int c = slot ^ (row & 7);
            ((uint4*)As)[L] = *(const uint4*)(&A[(size_t)(m0 + row) * KI2S + k0 + c * 8]);
            ((uint4*)Bs)[L] = *(const uint4*)(&B[(size_t)(p0 + row) * KI2S + k0 + c * 8]);
        }
        __syncthreads();
        for (int kk = 0; kk < 2; ++kk) {
            bf16x8 af[4], bfv[4];
            for (int mt = 0; mt < 4; ++mt) {
                int row = mhalf + mt * 16 + col;
                int slot = (kk * 4 + quad) ^ (row & 7);
                af[mt] = *(const bf16x8*)(&As[row * 64 + slot * 8]);
            }
            for (int nt = 0; nt < 4; ++nt) {
                int row = nhalf + nt * 16 + col;
                int slot = (kk * 4 + quad) ^ (row & 7);
                bfv[nt] = *(const bf16x8*)(&Bs[row * 64 + slot * 8]);
            }
            for (int mt = 0; mt < 4; ++mt)
                for (int nt = 0; nt < 4; ++nt)
                    acc[mt][nt] = __builtin_amdgcn_mfma_f32_16x16x32_bf16(
                        af[mt], bfv[nt], acc[mt][nt], 0, 0, 0);
        }
        __syncthreads();
    }
    for (int mt = 0; mt < 4; ++mt)
        for (int nt = 0; nt < 4; ++nt) {
            int m = m0 + mhalf + mt * 16 + quad * 4;
            int p = p0 + nhalf + nt * 16 + col;
            for (int r = 0; r < 4; ++r)
                Hout[(size_t)(m + r) * NP + p] = (bf16)acc[mt][nt][r];
        }
}

// ============================================================
// Cooperative row scan: 192 blocks = 16 batches x 12 feature-chunks(16f).
// Fence-free protocol:
//  - h exchange + counters go through IC-coherent relaxed atomics only
//    (no wbl2/inv on the per-row path).
//  - arrival: per-wave vmcnt(0) drain of its sc1 publish stores, then
//    lane0 count. Target = 48 arrivals/row per batch.
//  - skip GEMM (reads hlds = h(y-1), untouched by LSTM which writes a
//    separate hnew buffer) runs in the spin shadow; Hbuf gate-bias
//    prefetch for row y+1 is issued before the spin.
// ============================================================
__global__ __launch_bounds__(256) void scan_kernel(
    const bf16* __restrict__ Hbuf,   // [768][65536]
    const bf16* __restrict__ Ws2s,   // [768][576]
    const bf16* __restrict__ Wskip,  // [384][192]
    const float* __restrict__ x,
    const float* __restrict__ b_skip,
    float* __restrict__ out,
    bf16* __restrict__ hg,           // [3][16][66*192]
    unsigned* __restrict__ cnt) {    // [16][32] padded counters
    cooperative_groups::grid_group grid = cooperative_groups::this_grid();
    __shared__ __align__(16) bf16 hlds[66 * 200];   // staged full h row (halo idx)
    __shared__ __align__(16) bf16 hnew[64 * 20];    // own 16f slice of h(y)
    const int bid = blockIdx.x;
    const int b = (bid & 7) * 2 + (bid / 96);   // same-batch blocks share bid%8
    const int j = (bid >> 3) % 12;
    const int tid = threadIdx.x, lane = tid & 63, wid = tid >> 6;
    const int quad = lane >> 4, col = lane & 15;

    // ---- init: zero hg + counters (plain stores; grid.sync's fences push
    // them to IC) + zero hlds (h(-1) = 0) ----
    {
        const int total = 3 * 16 * 66 * 192 / 2;   // dwords
        for (int i = bid * 256 + tid; i < total; i += NBLK * 256)
            ((unsigned*)hg)[i] = 0u;
        if (tid < 32) cnt[(bid % 16) * 32 + tid] = 0u;
        for (int i = tid; i < 66 * 100; i += 256) ((unsigned*)hlds)[i] = 0u;
    }
    // persistent A fragments
    bf16x8 Ag[18];
    {
        int f = 16 * j + wid * 4 + (col >> 2), q = col & 3;
        const bf16* Arow = Ws2s + (size_t)(q * 192 + f) * KS2S + quad * 8;
        for (int kc = 0; kc < 18; ++kc) Ag[kc] = *(const bf16x8*)(Arow + kc * 32);
    }
    bf16x8 Ak[6];
    const int mtk = wid & 1, ntk0 = (wid >> 1) * 2;
    {
        int co = 32 * j + mtk * 16 + col;
        const bf16* Krow = Wskip + (size_t)co * FEAT + quad * 8;
        for (int kc = 0; kc < 6; ++kc) Ak[kc] = *(const bf16x8*)(Krow + kc * 32);
    }
    const int fmine = 16 * j + wid * 4 + quad;
    const int lf = wid * 4 + quad;              // local feature 0..15
    float cstate[4] = {0.f, 0.f, 0.f, 0.f};
    unsigned* mycnt = cnt + b * 32;
    grid.sync();   // one-time: init visibility (its fences flush zeros to IC)

    const size_t pbase = (size_t)b * HH * WW;
    float hadd[4][4];
    {   // prefetch Hbuf gate biases for row 0
        for (int nt = 0; nt < 4; ++nt) {
            int w = nt * 16 + col;
            for (int r = 0; r < 4; ++r)
                hadd[nt][r] = (float)Hbuf[(size_t)(r * FEAT + fmine) * NP + pbase + w];
        }
    }

    for (int y = 0; y < 64; ++y) {
        // ---- gates GEMM: s = Ws2s_slice * im2col(h(y-1)) ----
        f32x4 acc[4] = {};
        for (int kc = 0; kc < 18; ++kc) {
            int k0 = kc * 32 + quad * 8;
            int t = k0 / FEAT, f = k0 % FEAT;
            for (int nt = 0; nt < 4; ++nt) {
                int w = nt * 16 + col;
                bf16x8 bfr = *(const bf16x8*)(&hlds[(w + t) * 200 + f]);
                acc[nt] = __builtin_amdgcn_mfma_f32_16x16x32_bf16(Ag[kc], bfr, acc[nt], 0, 0, 0);
            }
        }
        // ---- LSTM update -> hnew (hlds stays = h(y-1) for skip GEMM) ----
        for (int nt = 0; nt < 4; ++nt) {
            int w = nt * 16 + col;
            float so = acc[nt][0] + hadd[nt][0];
            float sf = acc[nt][1] + hadd[nt][1];
            float si = acc[nt][2] + hadd[nt][2];
            float sg = acc[nt][3] + hadd[nt][3];
            float go = sigm_fast(so);
            float gf = sigm_fast(sf);
            float gi = sigm_fast(si);
            float gg = sigm_fast(sg);
            float cc = gf * cstate[nt] + gi * gg;
            cstate[nt] = cc;
            hnew[w * 20 + lf] = (bf16)(go * tanh_fast(cc));
        }
        __syncthreads();   // hnew complete across threads

        // ---- publish own 16f slice of h(y) -> hg[y%3][b] (IC stores) ----
        {
            bf16* dst = hg + ((size_t)(y % 3) * 16 + b) * (66 * 192);
            int w = tid >> 2, fo = (tid & 3) * 4;
            u64 v = *(const u64*)(&hnew[w * 20 + fo]);
            ic_store64((u64*)(dst + (size_t)(w + 1) * 192 + 16 * j + fo), v);
        }
        // per-wave arrival: drain own sc1 stores to IC, then count.
        asm volatile("s_waitcnt vmcnt(0)" ::: "memory");
        if (lane == 0)
            __hip_atomic_fetch_add(mycnt, 1u, __ATOMIC_RELAXED, __HIP_MEMORY_SCOPE_AGENT);

        // ---- prefetch Hbuf gate biases for row y+1 (hides HBM latency
        // under skip GEMM + spin + stage) ----
        if (y < 63) {
            const size_t prow = pbase + (size_t)(y + 1) * WW;
            for (int nt = 0; nt < 4; ++nt) {
                int w = nt * 16 + col;
                for (int r = 0; r < 4; ++r)
                    hadd[nt][r] = (float)Hbuf[(size_t)(r * FEAT + fmine) * NP + prow + w];
            }
        }

        // ---- skip GEMM + residual out for row y-1 (spin shadow) ----
        if (y > 0) {
            const int ym = y - 1;
            f32x4 acc2[2] = {};
            for (int kc = 0; kc < 6; ++kc)
                for (int i = 0; i < 2; ++i) {
                    int w = (ntk0 + i) * 16 + col;
                    bf16x8 bfr = *(const bf16x8*)(&hlds[(w + 1) * 200 + kc * 32 + quad * 8]);
                    acc2[i] = __builtin_amdgcn_mfma_f32_16x16x32_bf16(Ak[kc], bfr, acc2[i], 0, 0, 0);
                }
            for (int r = 0; r < 4; ++r) {
                int co = 32 * j + mtk * 16 + quad * 4 + r;
                float bs = b_skip[co];
                for (int i = 0; i < 2; ++i) {
                    int w = (ntk0 + i) * 16 + col;
                    size_t xi = ((size_t)(b * CINCH + co) * HH + ym) * WW + w;
                    out[xi] = x[xi] + bs + acc2[i][r];
                }
            }
        }

        // ---- wait for all 48 wave-arrivals of this batch (row y) ----
        if (tid == 0) {
            unsigned target = 48u * (unsigned)(y + 1);
            while (__hip_atomic_load(mycnt, __ATOMIC_RELAXED, __HIP_MEMORY_SCOPE_AGENT) < target)
                __builtin_amdgcn_s_sleep(1);
        }
        __syncthreads();   // release; also orders prior hlds reads before restage

        // ---- stage h(y) -> hlds (IC loads, 8B units) ----
        {
            const u64* src = (const u64*)(hg + ((size_t)(y % 3) * 16 + b) * (66 * 192));
            #pragma unroll
            for (int it = 0; it < 13; ++it) {
                int c = it * 256 + tid;
                if (c < 66 * 48) {
                    u64 v = ic_load64(src + c);
                    int w = c / 48, fc = c % 48;
                    *(u64*)(&hlds[w * 200 + fc * 4]) = v;
                }
            }
        }
        __syncthreads();
    }

    // ---- epilogue: skip GEMM + residual for row 63 (hlds = h(63)) ----
    {
        const int ym = 63;
        f32x4 acc2[2] = {};
        for (int kc = 0; kc < 6; ++kc)
            for (int i = 0; i < 2; ++i) {
                int w = (ntk0 + i) * 16 + col;
                bf16x8 bfr = *(const bf16x8*)(&hlds[(w + 1) * 200 + kc * 32 + quad * 8]);
                acc2[i] = __builtin_amdgcn_mfma_f32_16x16x32_bf16(Ak[kc], bfr, acc2[i], 0, 0, 0);
            }
        for (int r = 0; r < 4; ++r) {
            int co = 32 * j + mtk * 16 + quad * 4 + r;
            float bs = b_skip[co];
            for (int i = 0; i < 2; ++i) {
                int w = (ntk0 + i) * 16 + col;
                size_t xi = ((size_t)(b * CINCH + co) * HH + ym) * WW + w;
                out[xi] = x[xi] + bs + acc2[i][r];
            }
        }
    }
}

// ============================================================
extern "C" void kernel_launch(void* const* d_in, const int* in_sizes, int n_in,
                              void* d_out, int out_size, void* d_ws, size_t ws_size,
                              hipStream_t stream) {
    const float* x      = (const float*)d_in[0];
    const float* w_i2s  = (const float*)d_in[1];
    const float* w_s2s  = (const float*)d_in[2];
    const float* w_skip = (const float*)d_in[3];
    const float* b_skip = (const float*)d_in[4];
    float* out = (float*)d_out;

    char* ws = (char*)d_ws;
    const size_t HBUF_B = (size_t)CGATE * NP * 2;        // 100,663,296
    bf16* Hbuf = (bf16*)ws;
    size_t off = HBUF_B;
    bf16* WpA  = (bf16*)(ws + off); off += (size_t)CGATE * KI2S * 2;
    bf16* WpS  = (bf16*)(ws + off); off += (size_t)CGATE * KS2S * 2;
    bf16* WpK  = (bf16*)(ws + off); off += (size_t)CINCH * FEAT * 2;
    bf16* hg   = (bf16*)(ws + off); off += (size_t)3 * 16 * 66 * 192 * 2;
    unsigned* cnt = (unsigned*)(ws + off);               // 16*32 u32 = 2 KB
    bf16* Xp   = (bf16*)d_out;   // im2col scratch in d_out; dead before scan writes out

    pack_weights<<<256, 256, 0, stream>>>(w_i2s, w_s2s, w_skip, WpA, WpS, WpK);
    pack_x<<<BATCH * HH, 256, 0, stream>>>(x, Xp);
    dim3 g3(NP / 128, CGATE / 128);
    gemm_i2s<<<g3, 256, 0, stream>>>(WpA, Xp, Hbuf);

    void* args[] = { (void*)&Hbuf, (void*)&WpS, (void*)&WpK,
                     (void*)&x, (void*)&b_skip, (void*)&out, (void*)&hg, (void*)&cnt };
    hipLaunchCooperativeKernel((const void*)scan_kernel, dim3(NBLK), dim3(256),
                               args, 0, stream);
}